// Round 1
// baseline (615.234 us; speedup 1.0000x reference)
//
#include <hip/hip_runtime.h>
#include <hip/hip_bf16.h>
#include <stdint.h>

#define IN_F 4096
#define OUT_F 4096
#define NOUT 40
#define KPAD 4160   // 4096 + 64 (40 outlier cols + 24 zero pad) = 65 * 64
#define M_TOT 8192  // 4*2048

// 256x256 tile, BK=64, 8 waves (2M x 4N), counted-vmcnt pipeline
#define BM 256
#define BN 256
#define BK 64
#define KTILES 65   // KPAD / BK

typedef float f32x4 __attribute__((ext_vector_type(4)));
typedef __bf16 bf16x8 __attribute__((ext_vector_type(8)));

typedef __attribute__((address_space(1))) void GV;
typedef __attribute__((address_space(3))) void LV;
#define GLDS16(gp, lp) \
  __builtin_amdgcn_global_load_lds((GV*)(gp), (LV*)(lp), 16, 0, 0)

__device__ __forceinline__ unsigned short f2bf(float f) {
  unsigned u = __float_as_uint(f);
  u += 0x7FFFu + ((u >> 16) & 1u);
  return (unsigned short)(u >> 16);
}

// ---- masked global abs-max over x (fp32), outlier mask as LDS bitmap ----
__global__ void k_absmax(const float4* __restrict__ x4, const int* __restrict__ oidx,
                         unsigned* __restrict__ out) {
  __shared__ unsigned bits[128];  // 4096-bit outlier-channel mask
  const int t = threadIdx.x;
  if (t < 128) bits[t] = 0;
  __syncthreads();
  if (t < NOUT) {
    int c = oidx[t];
    atomicOr(&bits[c >> 5], 1u << (c & 31));
  }
  __syncthreads();
  const int n4 = M_TOT * IN_F / 4;
  float m = 0.f;
  const int stride = gridDim.x * blockDim.x;
  for (int i = blockIdx.x * blockDim.x + t; i < n4; i += stride) {
    float4 u = x4[i];
    unsigned wb = bits[(i & 1023) >> 3];  // word for columns (i*4 .. i*4+3) % 4096
    int sh = (i & 7) * 4;
    m = fmaxf(m, ((wb >> (sh + 0)) & 1) ? 0.f : fabsf(u.x));
    m = fmaxf(m, ((wb >> (sh + 1)) & 1) ? 0.f : fabsf(u.y));
    m = fmaxf(m, ((wb >> (sh + 2)) & 1) ? 0.f : fabsf(u.z));
    m = fmaxf(m, ((wb >> (sh + 3)) & 1) ? 0.f : fabsf(u.w));
  }
#pragma unroll
  for (int off = 32; off; off >>= 1) m = fmaxf(m, __shfl_down(m, off, 64));
  if ((t & 63) == 0) atomicMax(out, __float_as_uint(m));
}

// ---- A' = [rint(clip(x)*127/upper) | (x - clip(x))*127/upper on outlier cols | 0] ----
__global__ void k_prep_a(const float* __restrict__ x,
                         const int* __restrict__ oidx,
                         const unsigned* __restrict__ upper_bits,
                         unsigned short* __restrict__ A) {
  const int m = blockIdx.x;
  const int t = threadIdx.x;
  const float upper = __uint_as_float(*upper_bits);
  const float inv = 127.0f / fmaxf(upper, 1e-5f);
  const float4* xr = (const float4*)(x + (size_t)m * IN_F);
  uint4* Ar = (uint4*)(A + (size_t)m * KPAD);
#pragma unroll
  for (int rep = 0; rep < 2; ++rep) {
    const int c = t + rep * 256;
    float4 u0 = xr[2 * c];
    float4 u1 = xr[2 * c + 1];
    float f[8] = {u0.x, u0.y, u0.z, u0.w, u1.x, u1.y, u1.z, u1.w};
    unsigned o[4];
#pragma unroll
    for (int w = 0; w < 4; ++w) {
      float a = fminf(fmaxf(f[2 * w], -upper), upper);
      float b = fminf(fmaxf(f[2 * w + 1], -upper), upper);
      unsigned short b0 = f2bf(rintf(a * inv));
      unsigned short b1 = f2bf(rintf(b * inv));
      o[w] = (unsigned)b0 | ((unsigned)b1 << 16);
    }
    uint4 ov; ov.x = o[0]; ov.y = o[1]; ov.z = o[2]; ov.w = o[3];
    Ar[c] = ov;
  }
  if (t < 64) {
    unsigned short v = 0;
    if (t < NOUT) {
      float xf = x[(size_t)m * IN_F + oidx[t]];
      float xc = fminf(fmaxf(xf, -upper), upper);
      v = f2bf((xf - xc) * inv);
    }
    A[(size_t)m * KPAD + IN_F + t] = v;
  }
}

// ---- W' = [W | B | 0] as bf16 [OUT_F][KPAD] ----
__global__ void k_prep_w(const float* __restrict__ w, const float* __restrict__ Bm,
                         unsigned short* __restrict__ W) {
  const int o = blockIdx.x;
  const int t = threadIdx.x;
  const float4* wr = (const float4*)(w + (size_t)o * IN_F);
  uint4* Wr = (uint4*)(W + (size_t)o * KPAD);
#pragma unroll
  for (int rep = 0; rep < 2; ++rep) {
    const int c = t + rep * 256;
    float4 u0 = wr[2 * c];
    float4 u1 = wr[2 * c + 1];
    uint4 ov;
    ov.x = (unsigned)f2bf(u0.x) | ((unsigned)f2bf(u0.y) << 16);
    ov.y = (unsigned)f2bf(u0.z) | ((unsigned)f2bf(u0.w) << 16);
    ov.z = (unsigned)f2bf(u1.x) | ((unsigned)f2bf(u1.y) << 16);
    ov.w = (unsigned)f2bf(u1.z) | ((unsigned)f2bf(u1.w) << 16);
    Wr[c] = ov;
  }
  if (t < 64)
    W[(size_t)o * KPAD + IN_F + t] =
        (t < NOUT) ? f2bf(Bm[(size_t)o * NOUT + t]) : (unsigned short)0;
}

// ---- main GEMM: 256x256 tile, BK=64, 8 waves, double-buffered LDS,
//      counted s_waitcnt vmcnt(8) (never drained in steady state), raw barriers,
//      3-bit XOR LDS swizzle (slot ^= row&7) realized via pre-swizzled global src.
__global__ __launch_bounds__(512, 2) void k_gemm(
    const unsigned short* __restrict__ A, const unsigned short* __restrict__ W,
    const float* __restrict__ bias, const unsigned* __restrict__ upper_bits,
    float* __restrict__ out) {
  // 2 buffers x 256 rows x 64 k bf16 per matrix = 32 KB each -> 128 KB total
  __shared__ __attribute__((aligned(16))) unsigned short As[2][BM * BK];
  __shared__ __attribute__((aligned(16))) unsigned short Ws[2][BN * BK];

  const int t = threadIdx.x;

  // T1: bijective XCD swizzle (512 % 8 == 0). Within an XCD chunk of 64 wgs,
  // n-fastest: 16 consecutive wgs share one 2.13 MB A-panel (L2-resident).
  const int wg = ((int)blockIdx.x & 7) * 64 + ((int)blockIdx.x >> 3);
  const int bm = (wg >> 4) * BM;   // 32 m-tiles
  const int bn = (wg & 15) * BN;   // 16 n-tiles

  const int lane = t & 63;
  const int wave = t >> 6;                 // 0..7
  const int wm = (wave >> 2) * 128;        // 2 waves in M
  const int wn = (wave & 3) * 64;          // 4 waves in N
  const int lrow = lane & 15, lquad = lane >> 4;

  f32x4 acc[8][4] = {};

  // ---- staging addresses (T2: swizzle via global source; LDS dest stays linear)
  // thread t writes LDS row (t>>3)+64L, 16B-slot (t&7); that slot must hold
  // global k-slot (t&7) ^ (row&7) = (t&7) ^ ((t>>3)&7)  (thread-constant).
  const int kswz = (((t & 7) ^ ((t >> 3) & 7)) * 8);  // elements
  const unsigned short* Ag = A + (size_t)(bm + (t >> 3)) * KPAD + kswz;
  const unsigned short* Wg = W + (size_t)(bn + (t >> 3)) * KPAD + kswz;
  char* ldsA0 = (char*)&As[0][0] + t * 16;
  char* ldsA1 = (char*)&As[1][0] + t * 16;
  char* ldsW0 = (char*)&Ws[0][0] + t * 16;
  char* ldsW1 = (char*)&Ws[1][0] + t * 16;
  const size_t rstep = (size_t)64 * KPAD;

#define STAGE_TILE(lA, lW, k0)                      \
  do {                                              \
    GLDS16(Ag + (k0), (lA));                        \
    GLDS16(Ag + (k0) + rstep, (lA) + 8192);         \
    GLDS16(Ag + (k0) + 2 * rstep, (lA) + 16384);    \
    GLDS16(Ag + (k0) + 3 * rstep, (lA) + 24576);    \
    GLDS16(Wg + (k0), (lW));                        \
    GLDS16(Wg + (k0) + rstep, (lW) + 8192);         \
    GLDS16(Wg + (k0) + 2 * rstep, (lW) + 16384);    \
    GLDS16(Wg + (k0) + 3 * rstep, (lW) + 24576);    \
  } while (0)

  // ---- fragment-read swizzle: physical slot = logical slot ^ (row&7);
  // row&7 == lrow&7 for all fragment rows (wm, i*16 multiples of 8).
  const int x7 = lrow & 7;
  const int s0 = ((lquad) ^ x7) * 8;       // k-chunk 0 (logical slots 0..3)
  const int s1 = ((4 + lquad) ^ x7) * 8;   // k-chunk 1 (logical slots 4..7)

  // ---- prologue: stage tiles 0,1; wait tile 0 only (tile 1 stays in flight)
  STAGE_TILE(ldsA0, ldsW0, 0);
  STAGE_TILE(ldsA1, ldsW1, BK);
  asm volatile("s_waitcnt vmcnt(8)\n\ts_barrier" ::: "memory");

  for (int j = 0; j < KTILES; ++j) {
    const int b = j & 1;
    const unsigned short* Ab = b ? &As[1][0] : &As[0][0];
    const unsigned short* Wb = b ? &Ws[1][0] : &Ws[0][0];

    bf16x8 av[8][2], bv[4][2];
#pragma unroll
    for (int c = 0; c < 2; ++c) {
      const int sc = c ? s1 : s0;
#pragma unroll
      for (int jj = 0; jj < 4; ++jj)
        bv[jj][c] = *(const bf16x8*)(Wb + (wn + jj * 16 + lrow) * BK + sc);
#pragma unroll
      for (int ii = 0; ii < 8; ++ii)
        av[ii][c] = *(const bf16x8*)(Ab + (wm + ii * 16 + lrow) * BK + sc);
    }

    if (j < KTILES - 2) {
      // all reads of buf b done -> free it, then prefetch tile j+2 into it
      asm volatile("s_waitcnt lgkmcnt(0)\n\ts_barrier" ::: "memory");
      char* lA = b ? ldsA1 : ldsA0;
      char* lW = b ? ldsW1 : ldsW0;
      STAGE_TILE(lA, lW, (j + 2) * BK);
    }

    __builtin_amdgcn_s_setprio(1);
#pragma unroll
    for (int c = 0; c < 2; ++c)
#pragma unroll
      for (int ii = 0; ii < 8; ++ii)
#pragma unroll
        for (int jj = 0; jj < 4; ++jj)
          acc[ii][jj] = __builtin_amdgcn_mfma_f32_16x16x32_bf16(
              av[ii][c], bv[jj][c], acc[ii][jj], 0, 0, 0);
    __builtin_amdgcn_s_setprio(0);

    if (j < KTILES - 2) {
      // tile j+1's 8 loads are the oldest outstanding; tile j+2's 8 may fly on
      asm volatile("s_waitcnt vmcnt(8)\n\ts_barrier" ::: "memory");
    } else if (j == KTILES - 2) {
      // nothing staged this iter; drain the final tile's loads once
      asm volatile("s_waitcnt vmcnt(0)\n\ts_barrier" ::: "memory");
    }
  }
#undef STAGE_TILE

  const float scale = fmaxf(__uint_as_float(*upper_bits), 1e-5f) * (1.0f / 127.0f);
#pragma unroll
  for (int ii = 0; ii < 8; ++ii) {
    const int row = bm + wm + ii * 16 + lquad * 4;  // C/D: row = quad*4 + reg
#pragma unroll
    for (int jj = 0; jj < 4; ++jj) {
      const int col = bn + wn + jj * 16 + lrow;     // C/D: col = lane & 15
      const float bs = bias[col];
#pragma unroll
      for (int r = 0; r < 4; ++r)
        out[(size_t)(row + r) * OUT_F + col] = scale * acc[ii][jj][r] + bs;
    }
  }
}

extern "C" void kernel_launch(void* const* d_in, const int* in_sizes, int n_in,
                              void* d_out, int out_size, void* d_ws, size_t ws_size,
                              hipStream_t stream) {
  (void)in_sizes; (void)n_in; (void)out_size; (void)ws_size;
  const float* x    = (const float*)d_in[0];  // fp32 [4,2048,4096]
  const float* w    = (const float*)d_in[1];  // fp32 [4096,4096]
  const float* B    = (const float*)d_in[2];  // fp32 [4096,40]
  const float* bias = (const float*)d_in[3];  // fp32 [1,4096]
  const int* oidx   = (const int*)d_in[4];    // int32 [40]
  float* out = (float*)d_out;                 // fp32 [4,2048,4096]

  char* ws = (char*)d_ws;
  unsigned* upper = (unsigned*)ws;                     // 4 B atomic slot
  unsigned short* Ap = (unsigned short*)(ws + 65536);  // 8192*4160*2 = 68 MB
  unsigned short* Wp = Ap + (size_t)M_TOT * KPAD;      // 4096*4160*2 = 34 MB

  hipMemsetAsync(upper, 0, 4, stream);
  k_absmax<<<2048, 256, 0, stream>>>((const float4*)x, oidx, upper);
  k_prep_a<<<M_TOT, 256, 0, stream>>>(x, oidx, upper, Ap);
  k_prep_w<<<OUT_F, 256, 0, stream>>>(w, B, Wp);
  k_gemm<<<(M_TOT / BM) * (OUT_F / BN), 512, 0, stream>>>(Ap, Wp, bias, upper, out);
}